// Round 2
// baseline (260.944 us; speedup 1.0000x reference)
//
#include <hip/hip_runtime.h>
#include <hip/hip_bf16.h>

// DotProductAttention (Swin windowed, masked softmax).
// n=1024, Q=K=256, d=32, num_windows=64, NUM_HEADS=8.
// Round 1 diagnosis: NaN could only come from vl==0 (int64 valid_lens misread)
// or fp32-vs-bf16 input misread. This round: runtime dtype detection + dual
// template path + NaN guards.

typedef __attribute__((ext_vector_type(8))) short short8;   // 8 bf16 = 4 VGPR
typedef __attribute__((ext_vector_type(4))) float floatx4;  // MFMA C/D

#define VT_STRIDE 264   // 256 + 8 pad
#define PS_STRIDE 264
#define NEGV -1000000.0f

__device__ __forceinline__ float bf2f(unsigned short u) {
    union { unsigned u; float f; } x; x.u = ((unsigned)u) << 16;
    return x.f;
}
__device__ __forceinline__ unsigned short f2bf(float f) {
    union { float f; unsigned u; } x; x.f = f;
    unsigned r = (x.u + 0x7fffu + ((x.u >> 16) & 1u)) >> 16;  // RNE
    return (unsigned short)r;
}

// ---- runtime input-format detection (writes flags to d_ws) ----
// flags[0] = 1 if float tensors are fp32 (else bf16)
// flags[1] = 1 if valid_lens is int64 (else int32)
__global__ void detect_kernel(const unsigned short* __restrict__ Qg,
                              const int* __restrict__ VLg,
                              int* __restrict__ flags) {
    __shared__ int s_f32, s_vl64;
    const int tid = threadIdx.x;
    if (tid == 0) { s_f32 = 0; s_vl64 = 1; }
    __syncthreads();

    // bf16 exponent probe on Q's raw ushorts: e>=0xC0 (=|x|>=2^65) impossible
    // for N(0,1) bf16 data; near-certain among fp32 low halves.
    int f32_hit = 0;
    for (int i = tid; i < 4096; i += 256) {
        unsigned e = ((unsigned)Qg[i] >> 7) & 0xFFu;
        if (e >= 0xC0u) f32_hit = 1;
    }
    // valid_lens probe: first 1024 int32 words (safe for both layouts).
    // int64 buffer of values 1..256 -> all odd words are 0.
    // int32 buffer of values 1..256 -> odd words are nonzero.
    int odd_nonzero = 0;
    for (int i = tid; i < 1024; i += 256) {
        if ((i & 1) && VLg[i] != 0) odd_nonzero = 1;
    }
    if (f32_hit)     atomicOr(&s_f32, 1);
    if (odd_nonzero) atomicAnd(&s_vl64, 0);
    __syncthreads();
    if (tid == 0) { flags[0] = s_f32; flags[1] = s_vl64; }
}

// ---- fragment/mask/output helpers, templated on element dtype ----
template<bool F32>
__device__ __forceinline__ short8 load_frag8(const void* base, size_t elem_off) {
    if constexpr (!F32) {
        return *(const short8*)((const unsigned short*)base + elem_off);
    } else {
        const float* p = (const float*)base + elem_off;
        float4 a = *(const float4*)p;
        float4 b = *(const float4*)(p + 4);
        short8 r;
        r[0] = (short)f2bf(a.x); r[1] = (short)f2bf(a.y);
        r[2] = (short)f2bf(a.z); r[3] = (short)f2bf(a.w);
        r[4] = (short)f2bf(b.x); r[5] = (short)f2bf(b.y);
        r[6] = (short)f2bf(b.z); r[7] = (short)f2bf(b.w);
        return r;
    }
}

template<bool F32>
__device__ __forceinline__ float load_scalar(const void* base, size_t elem_off) {
    if constexpr (!F32) return bf2f(((const unsigned short*)base)[elem_off]);
    else                return ((const float*)base)[elem_off];
}

template<bool F32>
__device__ __forceinline__ void store_out(void* base, size_t elem_off, float v) {
    if constexpr (!F32) ((unsigned short*)base)[elem_off] = f2bf(v);
    else                ((float*)base)[elem_off] = v;
}

template<bool F32>
__global__ __launch_bounds__(256)
void attn_swin_kernel(const void* __restrict__ Qv,
                      const void* __restrict__ Kv,
                      const void* __restrict__ Vv,
                      const int* __restrict__ VLg,
                      const void* __restrict__ Wv,
                      void* __restrict__ Ov,
                      const int* __restrict__ flags)
{
    // uniform early-exit: only the variant matching the detected dtype runs
    const int is_f32 = flags[0];
    if ((is_f32 != 0) != F32) return;
    const int vl64 = flags[1];

    __shared__ __align__(16) unsigned short Vt[32 * VT_STRIDE];   // V^T: Vt[d][k]
    __shared__ __align__(16) unsigned short Psh[64 * PS_STRIDE];  // P rows

    const int b    = blockIdx.x;
    const int tid  = threadIdx.x;
    const int wave = tid >> 6;
    const int lane = tid & 63;
    const int c    = lane & 15;
    const int quad = lane >> 4;

    int vl;
    if (vl64) vl = (int)(((const long long*)VLg)[b]);
    else      vl = VLg[b];
    vl = min(max(vl, 0), 256);

    const int used16 = (vl + 15) >> 4;
    const int used32 = (vl + 31) >> 5;
    const int w_idx  = (b >> 3) & 63;
    const size_t bbase = (size_t)b * 8192;   // 256*32 elems / batch

    // ---- stage V transposed into LDS ----
    #pragma unroll
    for (int it = 0; it < 4; ++it) {
        const int d0 = it * 8;
        unsigned short tmp[8];
        if constexpr (!F32) {
            uint4 v = *(const uint4*)((const unsigned short*)Vv + bbase + (size_t)tid * 32 + d0);
            const unsigned short* pv = (const unsigned short*)&v;
            #pragma unroll
            for (int j = 0; j < 8; ++j) tmp[j] = pv[j];
        } else {
            const float* p = (const float*)Vv + bbase + (size_t)tid * 32 + d0;
            float4 a = *(const float4*)p;
            float4 d = *(const float4*)(p + 4);
            tmp[0] = f2bf(a.x); tmp[1] = f2bf(a.y); tmp[2] = f2bf(a.z); tmp[3] = f2bf(a.w);
            tmp[4] = f2bf(d.x); tmp[5] = f2bf(d.y); tmp[6] = f2bf(d.z); tmp[7] = f2bf(d.w);
        }
        #pragma unroll
        for (int j = 0; j < 8; ++j)
            Vt[(d0 + j) * VT_STRIDE + tid] = tmp[j];
    }
    __syncthreads();

    const float scale = 0.17677669529663687f;  // 1/sqrt(32)

    for (int qt = 0; qt < 4; ++qt) {
        short8 afrag = load_frag8<F32>(Qv, bbase + (size_t)(qt * 64 + wave * 16 + c) * 32 + quad * 8);

        // ---- S = Q K^T ----
        floatx4 acc[16];
        #pragma unroll
        for (int t = 0; t < 16; ++t) {
            if (t < used16) {
                short8 bfrag = load_frag8<F32>(Kv, bbase + (size_t)(t * 16 + c) * 32 + quad * 8);
                floatx4 z = {0.f, 0.f, 0.f, 0.f};
                acc[t] = __builtin_amdgcn_mfma_f32_16x16x32_bf16(afrag, bfrag, z, 0, 0, 0);
            }
        }

        // ---- scale + window mask + valid-len mask; row max ----
        const int qrow0 = qt * 64 + wave * 16 + quad * 4;
        const size_t wbase = (size_t)w_idx * 65536 + (size_t)qrow0 * 256 + c;

        float mrow[4] = {-3.0e38f, -3.0e38f, -3.0e38f, -3.0e38f};
        #pragma unroll
        for (int t = 0; t < 16; ++t) {
            if (t < used16) {
                const bool kvalid = (t * 16 + c) < vl;
                #pragma unroll
                for (int r = 0; r < 4; ++r) {
                    float s = acc[t][r] * scale + load_scalar<F32>(Wv, wbase + r * 256 + t * 16);
                    s = kvalid ? s : NEGV;
                    acc[t][r] = s;
                    mrow[r] = fmaxf(mrow[r], s);
                }
            }
        }
        #pragma unroll
        for (int r = 0; r < 4; ++r) {
            float m = mrow[r];
            m = fmaxf(m, __shfl_xor(m, 1));
            m = fmaxf(m, __shfl_xor(m, 2));
            m = fmaxf(m, __shfl_xor(m, 4));
            m = fmaxf(m, __shfl_xor(m, 8));
            mrow[r] = m;
        }

        // ---- exp + row sum ----
        float lrow[4] = {0.f, 0.f, 0.f, 0.f};
        #pragma unroll
        for (int t = 0; t < 16; ++t) {
            if (t < used16) {
                #pragma unroll
                for (int r = 0; r < 4; ++r) {
                    float p = __expf(acc[t][r] - mrow[r]);
                    acc[t][r] = p;
                    lrow[r] += p;
                }
            }
        }
        #pragma unroll
        for (int r = 0; r < 4; ++r) {
            float l = lrow[r];
            l += __shfl_xor(l, 1);
            l += __shfl_xor(l, 2);
            l += __shfl_xor(l, 4);
            l += __shfl_xor(l, 8);
            lrow[r] = l;
        }

        // ---- P (bf16) -> LDS, C-layout -> row-major ----
        const int tmax = used32 * 2;
        #pragma unroll
        for (int t = 0; t < 16; ++t) {
            if (t < tmax) {
                #pragma unroll
                for (int r = 0; r < 4; ++r) {
                    unsigned short pv = 0;
                    if (t < used16) pv = f2bf(acc[t][r]);
                    Psh[(wave * 16 + quad * 4 + r) * PS_STRIDE + t * 16 + c] = pv;
                }
            }
        }
        __syncthreads();

        // ---- O = P V ----
        floatx4 o0 = {0.f, 0.f, 0.f, 0.f}, o1 = {0.f, 0.f, 0.f, 0.f};
        #pragma unroll
        for (int kt = 0; kt < 8; ++kt) {
            if (kt < used32) {
                short8 pa  = *(const short8*)&Psh[(wave * 16 + c) * PS_STRIDE + kt * 32 + quad * 8];
                short8 vb0 = *(const short8*)&Vt[c * VT_STRIDE + kt * 32 + quad * 8];
                short8 vb1 = *(const short8*)&Vt[(16 + c) * VT_STRIDE + kt * 32 + quad * 8];
                o0 = __builtin_amdgcn_mfma_f32_16x16x32_bf16(pa, vb0, o0, 0, 0, 0);
                o1 = __builtin_amdgcn_mfma_f32_16x16x32_bf16(pa, vb1, o1, 0, 0, 0);
            }
        }

        // ---- normalize (guarded), store ----
        #pragma unroll
        for (int r = 0; r < 4; ++r) {
            const float rl = (lrow[r] > 0.f) ? (1.0f / lrow[r]) : 0.f;
            const size_t ob = bbase + (size_t)(qrow0 + r) * 32;
            store_out<F32>(Ov, ob + c,      o0[r] * rl);
            store_out<F32>(Ov, ob + 16 + c, o1[r] * rl);
        }
    }
}

extern "C" void kernel_launch(void* const* d_in, const int* in_sizes, int n_in,
                              void* d_out, int out_size, void* d_ws, size_t ws_size,
                              hipStream_t stream) {
    (void)in_sizes; (void)n_in; (void)out_size; (void)ws_size;
    const void* Qv  = d_in[0];
    const void* Kv  = d_in[1];
    const void* Vv  = d_in[2];
    const int*  VLg = (const int*)d_in[3];
    const void* Wv  = d_in[4];
    int* flags = (int*)d_ws;

    detect_kernel<<<dim3(1), dim3(256), 0, stream>>>((const unsigned short*)d_in[0], VLg, flags);
    attn_swin_kernel<false><<<dim3(1024), dim3(256), 0, stream>>>(Qv, Kv, Vv, VLg, Wv, d_out, flags);
    attn_swin_kernel<true ><<<dim3(1024), dim3(256), 0, stream>>>(Qv, Kv, Vv, VLg, Wv, d_out, flags);
}